// Round 5
// baseline (41.421 us; speedup 1.0000x reference)
//
#include <hip/hip_runtime.h>
#include <math.h>

#define NT 512
#define NB 256
#define VST 587                 // LDS row stride (mod 32 = 11); skewed storage below

// storage index for padded column j in [0,552): 17-float chunk pitch breaks the
// stride-16 bank pattern (lane addresses become 17c + const -> all 32 banks).
__device__ __forceinline__ int stidx(int j) { return j + (j >> 4); }

__global__ __launch_bounds__(NT, 2)
void dark_fused(const float* __restrict__ x, int* __restrict__ cnt,
                float* __restrict__ part, float* __restrict__ out) {
    __shared__ float Vs[32 * VST];      // 75.1 KB
    __shared__ float red[8];
    __shared__ int   last;

    const int tid = threadIdx.x;
    const int bid = blockIdx.x;
    const int swz = (bid & 7) * 32 + (bid >> 3);   // XCD k -> batches 2k,2k+1
    const int b   = swz >> 4;                      // 16 row-chunks per batch
    const int t   = swz & 15;                      // out rows 32t..32t+31
    const int col = tid;
    const float* xb = x + (size_t)b * 786432u + col;

    // ---- vertical sliding-min(35) of m = min_c(x) over 66 rows, in registers ----
    float w[66];
    #pragma unroll
    for (int k = 0; k < 66; ++k) {
        const int gh  = 32 * t - 17 + k;
        const int ghc = gh < 0 ? 0 : (gh > 511 ? 511 : gh);   // unconditional loads
        const float* p = xb + (size_t)ghc * 512u;
        const float m = fminf(p[0], fminf(p[262144], p[524288]));
        w[k] = ((unsigned)gh < 512u) ? m : 1.0f;              // pad never selected (x<1)
    }
    #pragma unroll
    for (int i = 0; i <= 64; ++i) w[i] = fminf(w[i], w[i + 1]);
    #pragma unroll
    for (int i = 0; i <= 62; ++i) w[i] = fminf(w[i], w[i + 2]);
    #pragma unroll
    for (int i = 0; i <= 58; ++i) w[i] = fminf(w[i], w[i + 4]);
    #pragma unroll
    for (int i = 0; i <= 50; ++i) w[i] = fminf(w[i], w[i + 8]);
    #pragma unroll
    for (int i = 0; i <= 34; ++i) w[i] = fminf(w[i], w[i + 16]);
    {
        const int sj = stidx(20 + col);
        #pragma unroll
        for (int k = 0; k < 32; ++k)                 // 35-min = min(min32[k], min32[k+3])
            Vs[k * VST + sj] = fminf(w[k], w[k + 3]);
    }
    if (col < 40) {                                  // pads: j 0..19 and 532..551
        const int sj = stidx(col < 20 ? col : 512 + col);
        #pragma unroll
        for (int k = 0; k < 32; ++k) Vs[k * VST + sj] = 1.0f;
    }
    __syncthreads();

    // ---- horizontal sliding-min(35) + sum(1 - min): 1024 tasks, 2 per thread ----
    float s = 0.0f;
    #pragma unroll
    for (int half = 0; half < 2; ++half) {
        const int task = tid + half * NT;
        const int r = task >> 5;                     // row 0..31
        const int c = task & 31;                     // 16-col output chunk
        const int base = r * VST + 17 * c + 3;       // skewed base of padded col 16c+3
        float h[53];
        #pragma unroll
        for (int i = 0; i < 53; ++i)                 // conflict-free: lanes at 17c spread
            h[i] = Vs[base + i + ((3 + i) >> 4)];
        #pragma unroll
        for (int i = 0; i <= 51; ++i) h[i] = fminf(h[i], h[i + 1]);
        #pragma unroll
        for (int i = 0; i <= 49; ++i) h[i] = fminf(h[i], h[i + 2]);
        #pragma unroll
        for (int i = 0; i <= 45; ++i) h[i] = fminf(h[i], h[i + 4]);
        #pragma unroll
        for (int i = 0; i <= 37; ++i) h[i] = fminf(h[i], h[i + 8]);
        #pragma unroll
        for (int i = 0; i <= 21; ++i) h[i] = fminf(h[i], h[i + 16]);
        #pragma unroll
        for (int kk = 0; kk < 16; ++kk) s += 1.0f - fminf(h[kk], h[kk + 3]);
    }

    // ---- block reduction ----
    #pragma unroll
    for (int off = 32; off; off >>= 1) s += __shfl_down(s, off);
    if ((tid & 63) == 0) red[tid >> 6] = s;
    __syncthreads();
    if (tid == 0) {
        float bs = 0.0f;
        #pragma unroll
        for (int i = 0; i < 8; ++i) bs += red[i];
        __hip_atomic_store(&part[bid], bs, __ATOMIC_RELEASE, __HIP_MEMORY_SCOPE_AGENT);
        const int old = __hip_atomic_fetch_add(cnt, 1, __ATOMIC_ACQ_REL,
                                               __HIP_MEMORY_SCOPE_AGENT);
        last = (old == NB - 1);
    }
    __syncthreads();

    // ---- last block: final reduce in fixed order (deterministic) ----
    if (last) {
        float s2 = (tid < NB)
            ? __hip_atomic_load(&part[tid], __ATOMIC_ACQUIRE, __HIP_MEMORY_SCOPE_AGENT)
            : 0.0f;
        #pragma unroll
        for (int off = 32; off; off >>= 1) s2 += __shfl_down(s2, off);
        if ((tid & 63) == 0) red[tid >> 6] = s2;
        __syncthreads();
        if (tid == 0) {
            float tot = 0.0f;
            #pragma unroll
            for (int i = 0; i < 8; ++i) tot += red[i];
            out[0] = -tot * (1.0f / 4194304.0f);     // -mean over 16*512*512
        }
    }
}

extern "C" void kernel_launch(void* const* d_in, const int* in_sizes, int n_in,
                              void* d_out, int out_size, void* d_ws, size_t ws_size,
                              hipStream_t stream) {
    const float* x = (const float*)d_in[0];
    float* out  = (float*)d_out;
    int*   cnt  = (int*)d_ws;                        // 4-byte arrival counter
    float* part = (float*)((char*)d_ws + 256);       // 256 partial sums

    hipMemsetAsync(d_ws, 0, 4, stream);              // zero counter (memset node)
    hipLaunchKernelGGL(dark_fused, dim3(NB), dim3(NT), 0, stream, x, cnt, part, out);
}